// Round 10
// baseline (310.757 us; speedup 1.0000x reference)
//
#include <hip/hip_runtime.h>
#include <hip/hip_cooperative_groups.h>
#include <math.h>

namespace cg = cooperative_groups;

typedef __attribute__((ext_vector_type(8))) short short8;
typedef __attribute__((ext_vector_type(4))) float f32x4;
typedef unsigned short ushort_t;

#define TSEQ   4096
#define NBATCH 4
#define DMODEL 768
#define HS     64
#define KS     4

static __device__ __forceinline__ ushort_t f2bf(float f) {
  union { float f; unsigned u; } v; v.f = f;
  unsigned r = v.u + 0x7fffu + ((v.u >> 16) & 1u);   // RNE
  return (ushort_t)(r >> 16);
}
static __device__ __forceinline__ float bf2f(ushort_t u) {
  union { unsigned u; float f; } v; v.u = ((unsigned)u) << 16; return v.f;
}

#define MFMA16(a,b,c) __builtin_amdgcn_mfma_f32_16x16x32_bf16((a),(b),(c),0,0,0)

// ============================================================================
// Round-10: ONE cooperative kernel.  Accounting across rounds 5-9 shows
// every compute kernel is <41 us but the pipeline is ~130 us: ~35-50 us is
// inter-launch gap/serialization (round-7's 3-launch probe: ~10 us/launch).
// Fusing all 4 phases with cg::grid().sync() removes 3 launches.  Unlike
// round-7's per-block __threadfence storm (fences interleaved with compute,
// 1024 L2-invalidates spread across the kernel -> 5x regression), grid-sync
// fences cluster at phase boundaries where the L2 writeback is required for
// cross-XCD visibility anyway and refills come from L3 (~1-2 us).
//   grid 512 x 256 thr, LDS 58368 B (qkv phase max) -> exactly 2 blocks/CU,
//   all 512 co-resident (cooperative requirement; VGPR fine).
//   phase 0 wprep   : blocks 0..35 (others idle to sync)     ~2 us
//   phase 1 qkv     : round-5 body verbatim, 512 blocks      ~31 us
//   phase 2 attn    : round-9 pair-balanced body, KS=4,
//                     32 pairs x 4 b x 4 s = 512 blocks, max 17 chunks;
//                     per-CU chunk work identical to round 9  ~40 us
//   phase 3 merge   : 512 blocks x 32 rows                   ~8 us
// ============================================================================
__global__ __launch_bounds__(256, 2) void fused_all(
    const float* __restrict__ x,  const float* __restrict__ Wq,
    const float* __restrict__ Wk, const float* __restrict__ Wv,
    ushort_t* __restrict__ Wt, ushort_t* __restrict__ q,
    ushort_t* __restrict__ kO, ushort_t* __restrict__ vT,
    float* __restrict__ ML, ushort_t* __restrict__ OP,
    float* __restrict__ out)
{
  // 58368 B shared, aliased per phase:
  //  wprep: float [64][65]                  (16640 B)
  //  qkv  : sA 2x32x72 u16 | sB 2x192x64 u16 (9216 + 49152)
  //  attn : sK 2x64x64 | sV 2x64x64 | sP 4x16x64 u16 (16384+16384+8192=40960)
  __shared__ __align__(16) ushort_t smem[29184];

  cg::grid_group grid = cg::this_grid();

  const int tid  = threadIdx.x;
  const int bid  = blockIdx.x;
  const int w    = tid >> 6;
  const int lane = tid & 63;
  const int l16  = lane & 15, quad = lane >> 4;

  // ---------------- phase 0: W prep (blocks 0..35) ----------------
  if (bid < 36) {
    float* lds = (float*)smem;                  // [64][65]
    const int m = bid / 12, kc = bid % 12, k0 = kc * 64;
    const float* W = (m == 0) ? Wq : (m == 1) ? Wk : Wv;
#pragma unroll
    for (int i = 0; i < 16; i++) {
      const int row = i * 4 + (tid >> 6), col = tid & 63;
      lds[row * 65 + col] = W[(size_t)(k0 + row) * HS + col];   // coalesced
    }
    __syncthreads();
#pragma unroll
    for (int i = 0; i < 16; i++) {
      const int n = i * 4 + (tid >> 6), kk = tid & 63;
      Wt[(size_t)(m * 64 + n) * DMODEL + k0 + kk] = f2bf(lds[kk * 65 + n]);
    }
  }
  grid.sync();

  // ---------------- phase 1: QKV projection (round-5 body) ----------------
  {
    ushort_t* sA = smem;                        // [2][32*72]
    ushort_t* sB = smem + 2 * 32 * 72;          // [2][192*64]
    const int M0 = bid * 32;

    const int arow = tid >> 3, acol = (tid & 7) * 8;
    const float* ax = x + (size_t)(M0 + arow) * DMODEL + acol;

    const int bcol_l = lane >> 3;
    const int bkoff  = (((lane & 7) ^ (bcol_l & 7)) << 3);

    f32x4 acc[2][3];
#pragma unroll
    for (int mt = 0; mt < 2; mt++)
#pragma unroll
      for (int nt = 0; nt < 3; nt++) acc[mt][nt] = (f32x4){0.f, 0.f, 0.f, 0.f};

    {
#pragma unroll
      for (int j = 0; j < 6; j++) {
        const int colb = w * 48 + j * 8;
        __builtin_amdgcn_global_load_lds(
            (const __attribute__((address_space(1))) ushort_t*)
                (Wt + (size_t)(colb + bcol_l) * DMODEL + bkoff),
            (__attribute__((address_space(3))) ushort_t*)(&sB[colb * 64]),
            16, 0, 0);
      }
      const float4 f0 = *(const float4*)(ax);
      const float4 f1 = *(const float4*)(ax + 4);
      short8 p;
      p[0]=f2bf(f0.x); p[1]=f2bf(f0.y); p[2]=f2bf(f0.z); p[3]=f2bf(f0.w);
      p[4]=f2bf(f1.x); p[5]=f2bf(f1.y); p[6]=f2bf(f1.z); p[7]=f2bf(f1.w);
      *(short8*)(&sA[arow * 72 + acol]) = p;
    }

    for (int ks = 0; ks < DMODEL / 64; ks++) {
      const int cur = ks & 1, nxt = cur ^ 1;
      __syncthreads();        // buf[cur] ready (drains prior gll + ds_write)

      float4 f0n, f1n;
      if (ks < DMODEL / 64 - 1) {
#pragma unroll
        for (int j = 0; j < 6; j++) {
          const int colb = w * 48 + j * 8;
          __builtin_amdgcn_global_load_lds(
              (const __attribute__((address_space(1))) ushort_t*)
                  (Wt + (size_t)(colb + bcol_l) * DMODEL + (ks + 1) * 64 + bkoff),
              (__attribute__((address_space(3))) ushort_t*)
                  (&sB[nxt * 192 * 64 + colb * 64]),
              16, 0, 0);
        }
        f0n = *(const float4*)(ax + (ks + 1) * 64);
        f1n = *(const float4*)(ax + (ks + 1) * 64 + 4);
      }

      const ushort_t* sAc = &sA[cur * 32 * 72];
      const ushort_t* sBc = &sB[cur * 192 * 64];
#pragma unroll
      for (int kc = 0; kc < 2; kc++) {
        const short8 a0 = *(const short8*)(sAc + (l16)      * 72 + kc * 32 + quad * 8);
        const short8 a1 = *(const short8*)(sAc + (16 + l16) * 72 + kc * 32 + quad * 8);
        const int kswz = (kc * 32 + quad * 8) ^ ((l16 & 7) << 3);
#pragma unroll
        for (int nt = 0; nt < 3; nt++) {
          const short8 bf =
              *(const short8*)(sBc + (w * 48 + nt * 16 + l16) * 64 + kswz);
          acc[0][nt] = MFMA16(a0, bf, acc[0][nt]);
          acc[1][nt] = MFMA16(a1, bf, acc[1][nt]);
        }
      }

      if (ks < DMODEL / 64 - 1) {
        short8 p;
        p[0]=f2bf(f0n.x); p[1]=f2bf(f0n.y); p[2]=f2bf(f0n.z); p[3]=f2bf(f0n.w);
        p[4]=f2bf(f1n.x); p[5]=f2bf(f1n.y); p[6]=f2bf(f1n.z); p[7]=f2bf(f1n.w);
        *(short8*)(&sA[nxt * 32 * 72 + arow * 72 + acol]) = p;
      }
    }

    // ---- epilogue: q direct; k swizzled; v via LDS transpose, swizzled ----
#pragma unroll
    for (int mt = 0; mt < 2; mt++)
#pragma unroll
      for (int nt = 0; nt < 3; nt++) {
        const int gnt = w * 3 + nt;
        const int mat = gnt >> 2;               // 0=q 1=k 2=v (wave-uniform)
        if (mat == 0) {
          const int col = (gnt & 3) * 16 + l16;
#pragma unroll
          for (int r = 0; r < 4; r++)
            q[(size_t)(M0 + mt * 16 + quad * 4 + r) * HS + col] =
                f2bf(acc[mt][nt][r] * 0.125f);
        } else if (mat == 1) {
          const int cb2 = (gnt & 3) * 2 + (l16 >> 3);
#pragma unroll
          for (int r = 0; r < 4; r++) {
            const int trow  = M0 + mt * 16 + quad * 4 + r;
            const int cphys = ((cb2 ^ (trow & 7)) << 3) | (l16 & 7);
            kO[(size_t)trow * HS + cphys] = f2bf(acc[mt][nt][r]);
          }
        }
      }
    __syncthreads();                            // K-loop LDS reads done
    float* vls = (float*)smem;                  // [32][65] fp32
#pragma unroll
    for (int mt = 0; mt < 2; mt++)
#pragma unroll
      for (int nt = 0; nt < 3; nt++) {
        const int gnt = w * 3 + nt;
        if ((gnt >> 2) == 2) {
          const int vcol = (gnt & 3) * 16 + l16;
#pragma unroll
          for (int r = 0; r < 4; r++)
            vls[(mt * 16 + quad * 4 + r) * 65 + vcol] = acc[mt][nt][r];
        }
      }
    __syncthreads();
    const int d = tid >> 2, seg = tid & 3;
    short8 pk;
#pragma unroll
    for (int i = 0; i < 8; i++) pk[i] = (short)f2bf(vls[(seg * 8 + i) * 65 + d]);
    {
      const int t0  = M0 & (TSEQ - 1);
      const int tb  = t0 & ~63;
      const int kb  = ((t0 & 63) >> 3) + seg;
      const int kbp = kb ^ (d & 7);
      *(short8*)(vT + ((size_t)(M0 >> 12) * HS + d) * TSEQ + tb + kbp * 8) = pk;
    }
  }
  grid.sync();

  // ---------------- phase 2: attention partials (round-9 body, KS=4) ------
  {
    ushort_t* sK = smem;                        // [2][64*64]
    ushort_t* sV = smem + 2 * 64 * 64;          // [2][64*64]
    ushort_t* sP = smem + 4 * 64 * 64;          // [4][16*64]

    const int s  = bid & 3;
    const int b  = (bid >> 2) & 3;
    const int jp = bid >> 4;                    // pair id 0..31

    const ushort_t* qg = q  + (size_t)b * TSEQ * HS;
    const ushort_t* kg = kO + (size_t)b * TSEQ * HS;
    const ushort_t* vg = vT + (size_t)b * HS * TSEQ;

    const int srow = lane >> 3;
    const int scol = (lane & 7) * 8;

#pragma unroll
    for (int h = 0; h < 2; h++) {
      const int j  = h ? jp : (63 - jp);        // long tile first
      const int R0 = j * 64 + w * 16;

      const short8 qf0 = *(const short8*)(qg + (size_t)(R0 + l16) * HS +      quad * 8);
      const short8 qf1 = *(const short8*)(qg + (size_t)(R0 + l16) * HS + 32 + quad * 8);

      f32x4 o[4];
#pragma unroll
      for (int dt = 0; dt < 4; dt++) o[dt] = (f32x4){0.f, 0.f, 0.f, 0.f};
      float mrow = -INFINITY, lrow = 0.f;

      const int nkt = j + 1;
      int kt = s, cur = 0;
      if (h) __syncthreads();                   // prior tile's LDS reads done
      if (kt < nkt) {
        const int k0 = kt * 64;
#pragma unroll
        for (int jj = 0; jj < 2; jj++) {
          const int r0 = w * 16 + jj * 8;
          __builtin_amdgcn_global_load_lds(
              (const __attribute__((address_space(1))) ushort_t*)
                  (kg + (size_t)(k0 + r0 + srow) * HS + scol),
              (__attribute__((address_space(3))) ushort_t*)(&sK[r0 * 64]),
              16, 0, 0);
          __builtin_amdgcn_global_load_lds(
              (const __attribute__((address_space(1))) ushort_t*)
                  (vg + (size_t)(r0 + srow) * TSEQ + k0 + scol),
              (__attribute__((address_space(3))) ushort_t*)(&sV[r0 * 64]),
              16, 0, 0);
        }
      }
      for (; kt < nkt; kt += KS) {
        const int k0 = kt * 64;
        __syncthreads();                        // buf[cur] staged & reads done
        if (kt + KS < nkt) {
          const int kn = (kt + KS) * 64;
#pragma unroll
          for (int jj = 0; jj < 2; jj++) {
            const int r0 = w * 16 + jj * 8;
            __builtin_amdgcn_global_load_lds(
                (const __attribute__((address_space(1))) ushort_t*)
                    (kg + (size_t)(kn + r0 + srow) * HS + scol),
                (__attribute__((address_space(3))) ushort_t*)
                    (&sK[(cur ^ 1) * 64 * 64 + r0 * 64]),
                16, 0, 0);
            __builtin_amdgcn_global_load_lds(
                (const __attribute__((address_space(1))) ushort_t*)
                    (vg + (size_t)(r0 + srow) * TSEQ + kn + scol),
                (__attribute__((address_space(3))) ushort_t*)
                    (&sV[(cur ^ 1) * 64 * 64 + r0 * 64]),
                16, 0, 0);
          }
        }
        const ushort_t* sKc = &sK[cur * 64 * 64];
        const ushort_t* sVc = &sV[cur * 64 * 64];
        const int sw = (l16 & 7) << 3;

        f32x4 sT[4];
        __builtin_amdgcn_s_setprio(1);
#pragma unroll
        for (int ct = 0; ct < 4; ct++) {
          sT[ct] = (f32x4){0.f, 0.f, 0.f, 0.f};
          const short8 kfa = *(const short8*)(sKc + (ct * 16 + l16) * 64 + ((quad * 8)      ^ sw));
          const short8 kfb = *(const short8*)(sKc + (ct * 16 + l16) * 64 + ((32 + quad * 8) ^ sw));
          sT[ct] = MFMA16(kfa, qf0, sT[ct]);
          sT[ct] = MFMA16(kfb, qf1, sT[ct]);
        }
        __builtin_amdgcn_s_setprio(0);
        if (k0 + 63 > R0) {                     // causal mask, diagonal only
          const int qrow = R0 + l16;
#pragma unroll
          for (int ct = 0; ct < 4; ct++)
#pragma unroll
            for (int r = 0; r < 4; r++)
              sT[ct][r] = (k0 + ct * 16 + quad * 4 + r <= qrow) ? sT[ct][r] : -INFINITY;
        }
        float tm = -INFINITY;
#pragma unroll
        for (int ct = 0; ct < 4; ct++)
#pragma unroll
          for (int r = 0; r < 4; r++) tm = fmaxf(tm, sT[ct][r]);
        tm = fmaxf(tm, __shfl_xor(tm, 16));
        tm = fmaxf(tm, __shfl_xor(tm, 32));
        const float mn = fmaxf(mrow, tm);
        const float al = __expf(mrow - mn);
        mrow = mn;
        float ps = 0.f;
#pragma unroll
        for (int ct = 0; ct < 4; ct++)
#pragma unroll
          for (int r = 0; r < 4; r++) { sT[ct][r] = __expf(sT[ct][r] - mn); ps += sT[ct][r]; }
        ps += __shfl_xor(ps, 16);
        ps += __shfl_xor(ps, 32);
        lrow = lrow * al + ps;

        ushort_t* Pw = &sP[w * 16 * 64];
#pragma unroll
        for (int ct = 0; ct < 4; ct++) {
          ushort4 pk;
          pk.x = f2bf(sT[ct][0]); pk.y = f2bf(sT[ct][1]);
          pk.z = f2bf(sT[ct][2]); pk.w = f2bf(sT[ct][3]);
          const int pb = (ct * 2 + (quad >> 1)) ^ (l16 & 7);
          *(ushort4*)(Pw + l16 * 64 + pb * 8 + (quad & 1) * 4) = pk;
        }
        float alo[4];
#pragma unroll
        for (int r = 0; r < 4; r++) alo[r] = __shfl(al, quad * 4 + r);
#pragma unroll
        for (int dt = 0; dt < 4; dt++)
#pragma unroll
          for (int r = 0; r < 4; r++) o[dt][r] *= alo[r];
        const short8 pf0 = *(const short8*)(Pw + l16 * 64 + (((quad)     ^ (l16 & 7)) << 3));
        const short8 pf1 = *(const short8*)(Pw + l16 * 64 + (((4 + quad) ^ (l16 & 7)) << 3));
        __builtin_amdgcn_s_setprio(1);
#pragma unroll
        for (int dt = 0; dt < 4; dt++) {
          const short8 vfa = *(const short8*)(sVc + (dt * 16 + l16) * 64 + ((quad * 8)      ^ sw));
          const short8 vfb = *(const short8*)(sVc + (dt * 16 + l16) * 64 + ((32 + quad * 8) ^ sw));
          o[dt] = MFMA16(pf0, vfa, o[dt]);
          o[dt] = MFMA16(pf1, vfb, o[dt]);
        }
        __builtin_amdgcn_s_setprio(0);
        cur ^= 1;
      }

      const size_t base = ((size_t)(b * KS + s) * TSEQ);
      if (quad == 0) {
        ML[(base + R0 + l16) * 2 + 0] = mrow;
        ML[(base + R0 + l16) * 2 + 1] = lrow;
      }
#pragma unroll
      for (int dt = 0; dt < 4; dt++)
#pragma unroll
        for (int r = 0; r < 4; r++)
          OP[(base + R0 + quad * 4 + r) * HS + dt * 16 + l16] = f2bf(o[dt][r]);
    }
  }
  grid.sync();

  // ---------------- phase 3: merge (512 blocks x 32 rows) ----------------
  {
    const int row = bid * 32 + (tid >> 3);      // 0..16383
    const int b   = row >> 12, t = row & (TSEQ - 1);
    const int d0  = (tid & 7) * 8;
    float m4[KS], l4[KS];
    float M = -INFINITY;
#pragma unroll
    for (int ss = 0; ss < KS; ss++) {
      const size_t i = ((size_t)(b * KS + ss) * TSEQ + t);
      m4[ss] = ML[i * 2]; l4[ss] = ML[i * 2 + 1];
      M = fmaxf(M, m4[ss]);
    }
    float den = 0.f;
    float n0=0.f,n1=0.f,n2=0.f,n3=0.f,n4=0.f,n5=0.f,n6=0.f,n7=0.f;
#pragma unroll
    for (int ss = 0; ss < KS; ss++) {
      const float a = __expf(m4[ss] - M);       // zero-trip split: weight 0
      den += l4[ss] * a;
      const size_t i = ((size_t)(b * KS + ss) * TSEQ + t);
      const ushort4 u0 = *(const ushort4*)(OP + i * HS + d0);
      const ushort4 u1 = *(const ushort4*)(OP + i * HS + d0 + 4);
      n0 += a * bf2f(u0.x); n1 += a * bf2f(u0.y);
      n2 += a * bf2f(u0.z); n3 += a * bf2f(u0.w);
      n4 += a * bf2f(u1.x); n5 += a * bf2f(u1.y);
      n6 += a * bf2f(u1.z); n7 += a * bf2f(u1.w);
    }
    const float inv = 1.f / den;
    float* op = out + (size_t)row * HS + d0;
    *(float4*)(op)     = make_float4(n0 * inv, n1 * inv, n2 * inv, n3 * inv);
    *(float4*)(op + 4) = make_float4(n4 * inv, n5 * inv, n6 * inv, n7 * inv);
  }
}

extern "C" void kernel_launch(void* const* d_in, const int* in_sizes, int n_in,
                              void* d_out, int out_size, void* d_ws, size_t ws_size,
                              hipStream_t stream) {
  const float* x  = (const float*)d_in[0];
  const float* Wq = (const float*)d_in[1];
  const float* Wk = (const float*)d_in[2];
  const float* Wv = (const float*)d_in[3];
  float* out = (float*)d_out;

  // ws: Wt 288K | q 2M | k 2M | vT 2M | ML 512K | OP 8M   (total ~15 MB)
  char* ws = (char*)d_ws;
  ushort_t* Wt = (ushort_t*)ws;
  ushort_t* qb = (ushort_t*)(ws + 294912);
  ushort_t* kb = (ushort_t*)(ws + 294912 + 2097152);
  ushort_t* vb = (ushort_t*)(ws + 294912 + 2 * 2097152);
  float*    ml = (float*)   (ws + 294912 + 3 * 2097152);
  ushort_t* op = (ushort_t*)(ws + 294912 + 3 * 2097152 + 524288);

  void* args[] = {(void*)&x,  (void*)&Wq, (void*)&Wk, (void*)&Wv,
                  (void*)&Wt, (void*)&qb, (void*)&kb, (void*)&vb,
                  (void*)&ml, (void*)&op, (void*)&out};
  hipLaunchCooperativeKernel((const void*)fused_all, dim3(512), dim3(256),
                             args, 0, stream);
}

// Round 11
// 128.500 us; speedup vs baseline: 2.4183x; 2.4183x over previous
//
#include <hip/hip_runtime.h>
#include <math.h>

typedef __attribute__((ext_vector_type(8))) short short8;
typedef __attribute__((ext_vector_type(4))) float f32x4;
typedef unsigned short ushort_t;

#define TSEQ   4096
#define NBATCH 4
#define DMODEL 768
#define HS     64
#define KSPLIT 8

static __device__ __forceinline__ ushort_t f2bf(float f) {
  union { float f; unsigned u; } v; v.f = f;
  unsigned r = v.u + 0x7fffu + ((v.u >> 16) & 1u);   // RNE
  return (ushort_t)(r >> 16);
}
static __device__ __forceinline__ float bf2f(ushort_t u) {
  union { unsigned u; float f; } v; v.u = ((unsigned)u) << 16; return v.f;
}

#define MFMA16(a,b,c) __builtin_amdgcn_mfma_f32_16x16x32_bf16((a),(b),(c),0,0,0)

// ---------------- W prep (coalesced LDS transpose) ----------------
// grid 36 = 3 mats x 12 k-chunks of 64.  Wt[n'=m*64+n][k] bf16.
__global__ __launch_bounds__(256) void wprep(
    const float* __restrict__ Wq, const float* __restrict__ Wk,
    const float* __restrict__ Wv, ushort_t* __restrict__ Wt)
{
  __shared__ float lds[64 * 65];
  const int m = blockIdx.x / 12, kc = blockIdx.x % 12, k0 = kc * 64;
  const float* W = (m == 0) ? Wq : (m == 1) ? Wk : Wv;
  const int tid = threadIdx.x;
#pragma unroll
  for (int i = 0; i < 16; i++) {
    const int row = i * 4 + (tid >> 6), col = tid & 63;
    lds[row * 65 + col] = W[(size_t)(k0 + row) * HS + col];   // coalesced
  }
  __syncthreads();
#pragma unroll
  for (int i = 0; i < 16; i++) {
    const int n = i * 4 + (tid >> 6), kk = tid & 63;
    Wt[(size_t)(m * 64 + n) * DMODEL + k0 + kk] = f2bf(lds[kk * 65 + n]);
  }
}

// ---------------- QKV projection: BM=64, 8-wave, dual-LDS dbuf GEMM --------
// Round-11: accounting fix -- dur_us includes the harness's ~42us ws-poison
// fill; qkv is really ~37us vs a ~10us floor.  Suspects: 512 blocks each
// re-reading the full 288KB Wt (147MB L2 traffic, 18MB/XCD through 4MB L2)
// and 24 barrier-drains/CU.  BM 32->64 @ 512 thr / 8 waves (grid 256 =
// 1 block/CU): halves Wt re-reads, halves barrier count, doubles MFMA per
// barrier.  LDS 67.6KB.  Wave (wm,wn) = (w>>2, w&3): rows wm*32+[0,32),
// cols wn*48+[0,48).  Staging/swizzle schema unchanged from round 5.
__global__ __launch_bounds__(512, 1) void qkv_mfma(
    const float* __restrict__ x, const ushort_t* __restrict__ Wt,
    ushort_t* __restrict__ q, ushort_t* __restrict__ kO, ushort_t* __restrict__ vT)
{
  __shared__ __align__(16) ushort_t sA[2][64 * 72];    // 18.4 KB
  __shared__ __align__(16) ushort_t sB[2][192 * 64];   // 48.0 KB

  const int tid  = threadIdx.x;
  const int w    = tid >> 6;                    // wave 0..7
  const int wm   = w >> 2, wn = w & 3;          // m-half, n-quarter
  const int lane = tid & 63;
  const int l16  = lane & 15, quad = lane >> 4;
  const int M0   = blockIdx.x * 64;

  // A staging: thread t covers row t/8, k-chunk (t%8)*8 (2 float4)
  const int arow = tid >> 3, acol = (tid & 7) * 8;
  const float* ax = x + (size_t)(M0 + arow) * DMODEL + acol;

  // B staging: wave w stages cols w*24..w*24+23 (3 x 1KB issues).
  // Pre-swizzled global k-offset (linear LDS dest + swizzled read).
  const int bcol_l = lane >> 3;                               // 0..7
  const int bkoff  = (((lane & 7) ^ (bcol_l & 7)) << 3);      // elems

  f32x4 acc[2][3];
#pragma unroll
  for (int mt = 0; mt < 2; mt++)
#pragma unroll
    for (int nt = 0; nt < 3; nt++) acc[mt][nt] = (f32x4){0.f, 0.f, 0.f, 0.f};

  // ---- prologue: stage tile 0 into buf 0
  {
#pragma unroll
    for (int j = 0; j < 3; j++) {
      const int colb = w * 24 + j * 8;
      __builtin_amdgcn_global_load_lds(
          (const __attribute__((address_space(1))) ushort_t*)
              (Wt + (size_t)(colb + bcol_l) * DMODEL + bkoff),
          (__attribute__((address_space(3))) ushort_t*)(&sB[0][colb * 64]),
          16, 0, 0);
    }
    const float4 f0 = *(const float4*)(ax);
    const float4 f1 = *(const float4*)(ax + 4);
    short8 p;
    p[0]=f2bf(f0.x); p[1]=f2bf(f0.y); p[2]=f2bf(f0.z); p[3]=f2bf(f0.w);
    p[4]=f2bf(f1.x); p[5]=f2bf(f1.y); p[6]=f2bf(f1.z); p[7]=f2bf(f1.w);
    *(short8*)(&sA[0][arow * 72 + acol]) = p;
  }

  for (int ks = 0; ks < DMODEL / 64; ks++) {
    const int cur = ks & 1, nxt = cur ^ 1;
    __syncthreads();          // buf[cur] ready (drains prior gll + ds_write)

    float4 f0n, f1n;
    if (ks < DMODEL / 64 - 1) {
#pragma unroll
      for (int j = 0; j < 3; j++) {
        const int colb = w * 24 + j * 8;
        __builtin_amdgcn_global_load_lds(
            (const __attribute__((address_space(1))) ushort_t*)
                (Wt + (size_t)(colb + bcol_l) * DMODEL + (ks + 1) * 64 + bkoff),
            (__attribute__((address_space(3))) ushort_t*)(&sB[nxt][colb * 64]),
            16, 0, 0);
      }
      f0n = *(const float4*)(ax + (ks + 1) * 64);
      f1n = *(const float4*)(ax + (ks + 1) * 64 + 4);
    }

    // ---- compute from buf[cur]
    const ushort_t* sAc = &sA[cur][0];
    const ushort_t* sBc = &sB[cur][0];
#pragma unroll
    for (int kc = 0; kc < 2; kc++) {
      const short8 a0 = *(const short8*)(sAc + (wm * 32 + l16)      * 72 + kc * 32 + quad * 8);
      const short8 a1 = *(const short8*)(sAc + (wm * 32 + 16 + l16) * 72 + kc * 32 + quad * 8);
      const int kswz = (kc * 32 + quad * 8) ^ ((l16 & 7) << 3);
#pragma unroll
      for (int nt = 0; nt < 3; nt++) {
        const short8 bf =
            *(const short8*)(sBc + (wn * 48 + nt * 16 + l16) * 64 + kswz);
        acc[0][nt] = MFMA16(a0, bf, acc[0][nt]);
        acc[1][nt] = MFMA16(a1, bf, acc[1][nt]);
      }
    }

    if (ks < DMODEL / 64 - 1) {          // convert + stage next A tile
      short8 p;
      p[0]=f2bf(f0n.x); p[1]=f2bf(f0n.y); p[2]=f2bf(f0n.z); p[3]=f2bf(f0n.w);
      p[4]=f2bf(f1n.x); p[5]=f2bf(f1n.y); p[6]=f2bf(f1n.z); p[7]=f2bf(f1n.w);
      *(short8*)(&sA[nxt][arow * 72 + acol]) = p;
    }
  }

  // ---- epilogue: q direct; k swizzled; v via LDS transpose, swizzled ----
#pragma unroll
  for (int mt = 0; mt < 2; mt++)
#pragma unroll
    for (int nt = 0; nt < 3; nt++) {
      const int gnt = wn * 3 + nt;              // 0..11
      const int mat = gnt >> 2;                 // 0=q 1=k 2=v (wave-uniform)
      if (mat == 0) {
        const int col = (gnt & 3) * 16 + l16;
#pragma unroll
        for (int r = 0; r < 4; r++)
          q[(size_t)(M0 + wm * 32 + mt * 16 + quad * 4 + r) * HS + col] =
              f2bf(acc[mt][nt][r] * 0.125f);
      } else if (mat == 1) {
        // k: 16B-block index of col, XOR'd with trow&7 (attn-staging swizzle)
        const int cb2 = (gnt & 3) * 2 + (l16 >> 3);
#pragma unroll
        for (int r = 0; r < 4; r++) {
          const int trow  = M0 + wm * 32 + mt * 16 + quad * 4 + r;
          const int cphys = ((cb2 ^ (trow & 7)) << 3) | (l16 & 7);
          kO[(size_t)trow * HS + cphys] = f2bf(acc[mt][nt][r]);
        }
      }
    }
  __syncthreads();                              // K-loop LDS reads done
  float* vls = (float*)&sA[0][0];               // [64][65] fp32 = 66.6 KB
#pragma unroll
  for (int mt = 0; mt < 2; mt++)
#pragma unroll
    for (int nt = 0; nt < 3; nt++) {
      const int gnt = wn * 3 + nt;
      if ((gnt >> 2) == 2) {
        const int vcol = (gnt & 3) * 16 + l16;
#pragma unroll
        for (int r = 0; r < 4; r++)
          vls[(wm * 32 + mt * 16 + quad * 4 + r) * 65 + vcol] = acc[mt][nt][r];
      }
    }
  __syncthreads();
  const int d = tid >> 3, seg = tid & 7;        // 64 dims x 8 segs of 8 t
  short8 pk;
#pragma unroll
  for (int i = 0; i < 8; i++) pk[i] = (short)f2bf(vls[(seg * 8 + i) * 65 + d]);
  // vT: key-block within 64-chunk XOR'd with d&7 (attn-staging swizzle)
  {
    const int tb  = M0 & (TSEQ - 1);            // M0 is 64-aligned
    const int kbp = seg ^ (d & 7);
    *(short8*)(vT + ((size_t)(M0 >> 12) * HS + d) * TSEQ + tb + kbp * 8) = pk;
  }
}

// ---------------- attention pass 1: partial flash attention ----------------
// Round-9 pair-balanced body (verbatim): each block processes complementary
// q-tiles (63-jp, jp) = 65 chunks/pair split KSPLIT=8 ways; grid 32 pairs x
// 4 batch x 8 splits = 1024 blocks, 4 blocks/CU, all co-resident.
__global__ __launch_bounds__(256, 4) void attn_part(
    const ushort_t* __restrict__ q, const ushort_t* __restrict__ k,
    const ushort_t* __restrict__ vT, float* __restrict__ ML, ushort_t* __restrict__ OP)
{
  __shared__ __align__(16) ushort_t sK[2][64 * 64];  // 16 KB  [key][d swz]
  __shared__ __align__(16) ushort_t sV[2][64 * 64];  // 16 KB  [d][key swz]
  __shared__ __align__(16) ushort_t sP[4][16 * 64];  //  8 KB  per-wave P swz

  const int idx  = blockIdx.x;
  const int s    = idx & 7;
  const int b    = (idx >> 3) & 3;
  const int jp   = idx >> 5;                   // pair id 0..31
  const int tid  = threadIdx.x;
  const int w    = tid >> 6;
  const int lane = tid & 63;
  const int l16  = lane & 15, quad = lane >> 4;

  const ushort_t* qg = q  + (size_t)b * TSEQ * HS;
  const ushort_t* kg = k  + (size_t)b * TSEQ * HS;
  const ushort_t* vg = vT + (size_t)b * HS * TSEQ;

  const int srow = lane >> 3;                  // staging: 8 rows/issue
  const int scol = (lane & 7) * 8;

#pragma unroll
  for (int h = 0; h < 2; h++) {
    const int j  = h ? jp : (63 - jp);         // long tile first
    const int R0 = j * 64 + w * 16;

    // Q B-operand frags (q pre-scaled 1/8, unswizzled): B[k=d][n=qrow]
    const short8 qf0 = *(const short8*)(qg + (size_t)(R0 + l16) * HS +      quad * 8);
    const short8 qf1 = *(const short8*)(qg + (size_t)(R0 + l16) * HS + 32 + quad * 8);

    f32x4 o[4];
#pragma unroll
    for (int dt = 0; dt < 4; dt++) o[dt] = (f32x4){0.f, 0.f, 0.f, 0.f};
    float mrow = -INFINITY, lrow = 0.f;        // per-lane qrow = R0 + l16

    const int nkt = j + 1;                     // 64-key chunks incl. diagonal
    int kt = s, cur = 0;
    if (h) __syncthreads();                    // prior tile's LDS reads done
    if (kt < nkt) {                            // prologue: stage chunk->buf0
      const int k0 = kt * 64;
#pragma unroll
      for (int jj = 0; jj < 2; jj++) {
        const int r0 = w * 16 + jj * 8;
        __builtin_amdgcn_global_load_lds(
            (const __attribute__((address_space(1))) ushort_t*)
                (kg + (size_t)(k0 + r0 + srow) * HS + scol),
            (__attribute__((address_space(3))) ushort_t*)(&sK[0][r0 * 64]),
            16, 0, 0);
        __builtin_amdgcn_global_load_lds(
            (const __attribute__((address_space(1))) ushort_t*)
                (vg + (size_t)(r0 + srow) * TSEQ + k0 + scol),
            (__attribute__((address_space(3))) ushort_t*)(&sV[0][r0 * 64]),
            16, 0, 0);
      }
    }
    for (; kt < nkt; kt += KSPLIT) {
      const int k0 = kt * 64;
      __syncthreads();                         // buf[cur] staged & prior reads done
      if (kt + KSPLIT < nkt) {                 // async stage next chunk
        const int kn = (kt + KSPLIT) * 64;
#pragma unroll
        for (int jj = 0; jj < 2; jj++) {
          const int r0 = w * 16 + jj * 8;
          __builtin_amdgcn_global_load_lds(
              (const __attribute__((address_space(1))) ushort_t*)
                  (kg + (size_t)(kn + r0 + srow) * HS + scol),
              (__attribute__((address_space(3))) ushort_t*)(&sK[cur ^ 1][r0 * 64]),
              16, 0, 0);
          __builtin_amdgcn_global_load_lds(
              (const __attribute__((address_space(1))) ushort_t*)
                  (vg + (size_t)(r0 + srow) * TSEQ + kn + scol),
              (__attribute__((address_space(3))) ushort_t*)(&sV[cur ^ 1][r0 * 64]),
              16, 0, 0);
        }
      }
      const ushort_t* sKc = &sK[cur][0];
      const ushort_t* sVc = &sV[cur][0];
      const int sw = (l16 & 7) << 3;           // row-XOR (elems; 16B blocks)

      // ---- S^T = K Q^T : C[key = ct*16+quad*4+r][qrow = l16] ----
      f32x4 sT[4];
      __builtin_amdgcn_s_setprio(1);
#pragma unroll
      for (int ct = 0; ct < 4; ct++) {
        sT[ct] = (f32x4){0.f, 0.f, 0.f, 0.f};
        const short8 kfa = *(const short8*)(sKc + (ct * 16 + l16) * 64 + ((quad * 8)      ^ sw));
        const short8 kfb = *(const short8*)(sKc + (ct * 16 + l16) * 64 + ((32 + quad * 8) ^ sw));
        sT[ct] = MFMA16(kfa, qf0, sT[ct]);
        sT[ct] = MFMA16(kfb, qf1, sT[ct]);
      }
      __builtin_amdgcn_s_setprio(0);
      if (k0 + 63 > R0) {                      // causal mask, diagonal only
        const int qrow = R0 + l16;
#pragma unroll
        for (int ct = 0; ct < 4; ct++)
#pragma unroll
          for (int r = 0; r < 4; r++)
            sT[ct][r] = (k0 + ct * 16 + quad * 4 + r <= qrow) ? sT[ct][r] : -INFINITY;
      }
      // ---- online softmax (per-lane row; 2 cross-quad shuffles) ----
      float tm = -INFINITY;
#pragma unroll
      for (int ct = 0; ct < 4; ct++)
#pragma unroll
        for (int r = 0; r < 4; r++) tm = fmaxf(tm, sT[ct][r]);
      tm = fmaxf(tm, __shfl_xor(tm, 16));
      tm = fmaxf(tm, __shfl_xor(tm, 32));
      const float mn = fmaxf(mrow, tm);
      const float al = __expf(mrow - mn);
      mrow = mn;
      float ps = 0.f;
#pragma unroll
      for (int ct = 0; ct < 4; ct++)
#pragma unroll
        for (int r = 0; r < 4; r++) { sT[ct][r] = __expf(sT[ct][r] - mn); ps += sT[ct][r]; }
      ps += __shfl_xor(ps, 16);
      ps += __shfl_xor(ps, 32);
      lrow = lrow * al + ps;
      // ---- P -> LDS (pitch 64, XOR-swizzled both sides), O rescale, PV ----
      ushort_t* Pw = &sP[w][0];
#pragma unroll
      for (int ct = 0; ct < 4; ct++) {
        ushort4 pk;
        pk.x = f2bf(sT[ct][0]); pk.y = f2bf(sT[ct][1]);
        pk.z = f2bf(sT[ct][2]); pk.w = f2bf(sT[ct][3]);
        const int pb = (ct * 2 + (quad >> 1)) ^ (l16 & 7);   // phys 8-elem block
        *(ushort4*)(Pw + l16 * 64 + pb * 8 + (quad & 1) * 4) = pk;
      }
      float alo[4];
#pragma unroll
      for (int r = 0; r < 4; r++) alo[r] = __shfl(al, quad * 4 + r);
#pragma unroll
      for (int dt = 0; dt < 4; dt++)
#pragma unroll
        for (int r = 0; r < 4; r++) o[dt][r] *= alo[r];
      const short8 pf0 = *(const short8*)(Pw + l16 * 64 + (((quad)     ^ (l16 & 7)) << 3));
      const short8 pf1 = *(const short8*)(Pw + l16 * 64 + (((4 + quad) ^ (l16 & 7)) << 3));
      __builtin_amdgcn_s_setprio(1);
#pragma unroll
      for (int dt = 0; dt < 4; dt++) {
        const short8 vfa = *(const short8*)(sVc + (dt * 16 + l16) * 64 + ((quad * 8)      ^ sw));
        const short8 vfb = *(const short8*)(sVc + (dt * 16 + l16) * 64 + ((32 + quad * 8) ^ sw));
        o[dt] = MFMA16(pf0, vfa, o[dt]);
        o[dt] = MFMA16(pf1, vfb, o[dt]);
      }
      __builtin_amdgcn_s_setprio(0);
      cur ^= 1;
    }

    // ---- partials: ML fp32 [B][KSPLIT][T][2], OP bf16 [B][KSPLIT][T][64] ----
    const size_t base = ((size_t)(b * KSPLIT + s) * TSEQ);
    if (quad == 0) {
      ML[(base + R0 + l16) * 2 + 0] = mrow;
      ML[(base + R0 + l16) * 2 + 1] = lrow;
    }
#pragma unroll
    for (int dt = 0; dt < 4; dt++)
#pragma unroll
      for (int r = 0; r < 4; r++)
        OP[(base + R0 + quad * 4 + r) * HS + dt * 16 + l16] = f2bf(o[dt][r]);
  }
}

// ---------------- attention pass 2: merge the KSPLIT partials ----------------
// Round-11: widened -- 16B OP loads (short8), 32B out stores, 8 dims/thread,
// 32 rows/block, grid 512.  ~21MB traffic -> ~5us target.
__global__ __launch_bounds__(256) void attn_merge(
    const float* __restrict__ ML, const ushort_t* __restrict__ OP,
    float* __restrict__ out)
{
  const int row = blockIdx.x * 32 + (threadIdx.x >> 3);   // 0..16383
  const int b   = row >> 12, t = row & (TSEQ - 1);
  const int d0  = (threadIdx.x & 7) * 8;
  float m[KSPLIT], l[KSPLIT];
  float M = -INFINITY;
#pragma unroll
  for (int ss = 0; ss < KSPLIT; ss++) {
    const size_t i = ((size_t)(b * KSPLIT + ss) * TSEQ + t);
    m[ss] = ML[i * 2]; l[ss] = ML[i * 2 + 1];
    M = fmaxf(M, m[ss]);
  }
  float den = 0.f;
  float n0=0.f,n1=0.f,n2=0.f,n3=0.f,n4=0.f,n5=0.f,n6=0.f,n7=0.f;
#pragma unroll
  for (int ss = 0; ss < KSPLIT; ss++) {
    const float a = __expf(m[ss] - M);          // zero-trip split: weight 0
    den += l[ss] * a;
    const size_t i = ((size_t)(b * KSPLIT + ss) * TSEQ + t);
    const short8 u = *(const short8*)(OP + i * HS + d0);
    n0 += a * bf2f((ushort_t)u[0]); n1 += a * bf2f((ushort_t)u[1]);
    n2 += a * bf2f((ushort_t)u[2]); n3 += a * bf2f((ushort_t)u[3]);
    n4 += a * bf2f((ushort_t)u[4]); n5 += a * bf2f((ushort_t)u[5]);
    n6 += a * bf2f((ushort_t)u[6]); n7 += a * bf2f((ushort_t)u[7]);
  }
  const float inv = 1.f / den;
  float* op = out + (size_t)row * HS + d0;
  *(float4*)(op)     = make_float4(n0 * inv, n1 * inv, n2 * inv, n3 * inv);
  *(float4*)(op + 4) = make_float4(n4 * inv, n5 * inv, n6 * inv, n7 * inv);
}

extern "C" void kernel_launch(void* const* d_in, const int* in_sizes, int n_in,
                              void* d_out, int out_size, void* d_ws, size_t ws_size,
                              hipStream_t stream) {
  const float* x  = (const float*)d_in[0];
  const float* Wq = (const float*)d_in[1];
  const float* Wk = (const float*)d_in[2];
  const float* Wv = (const float*)d_in[3];
  float* out = (float*)d_out;

  // ws: Wt 288K | q 2M | k 2M | vT 2M | ML 1M | OP 16M   (total ~23.6 MB)
  char* ws = (char*)d_ws;
  ushort_t* Wt = (ushort_t*)ws;
  ushort_t* qb = (ushort_t*)(ws + 294912);
  ushort_t* kb = (ushort_t*)(ws + 294912 + 2097152);
  ushort_t* vb = (ushort_t*)(ws + 294912 + 2 * 2097152);
  float*    ml = (float*)   (ws + 294912 + 3 * 2097152);
  ushort_t* op = (ushort_t*)(ws + 294912 + 3 * 2097152 + 1048576);

  wprep<<<36, 256, 0, stream>>>(Wq, Wk, Wv, Wt);
  qkv_mfma<<<(NBATCH * TSEQ) / 64, 512, 0, stream>>>(x, Wt, qb, kb, vb);
  attn_part<<<32 * NBATCH * KSPLIT, 256, 0, stream>>>(qb, kb, vb, ml, op);
  attn_merge<<<512, 256, 0, stream>>>(ml, op, out);
}